// Round 8
// baseline (4420.773 us; speedup 1.0000x reference)
//
#include <hip/hip_runtime.h>
#include <math.h>

// Glacier SIA stepper. 64 persistent blocks x 1024 threads.
// Each block = TWO 4-row bands (bandA rows aB..aB+3, bandB rows aB+4..aB+7),
// thread = (band, column). Per-band code identical to the 128-block version;
// the A<->B seam is exchanged through LDS (no MALL), only block<->block halos
// go through MALL publishes. Cross-block sync: depth-2 epoch-tagged ring of
// 64 slots, direct gather by wave 0, per-wave neighbor flag polls. Relaxed
// agent-scope atomics; no threadfences.
//
// Register-slot maps (per column j, band first-owned row al):
//   zs[s]  = Zs row al-2+s  (s=0..7; 0,7 halo)
//   Dv[ld] = D  row al-2+ld (ld=0..6; 0,6 halo)
//   h/hn/smbr/dH[ln] = row al-1+ln (ln=0..5); H row i needs D ld=ln,ln+1
//
// ws layout (bytes):
//   0     : ull ring[2][64] lines (stride 128 B) {epoch<<32 | blockMax bits}
//   32768 : float Ha[MM], Hb[MM], Da[MM], Db[MM]
// First 16384 B zeroed by captured hipMemsetAsync each call.

#define NN 512
#define MM (NN * NN)
#define NSTEPS 400
#define NBLK 64
#define TPB 1024

typedef unsigned long long ull;

__device__ __forceinline__ ull ald(const ull* p) {
  return __hip_atomic_load(p, __ATOMIC_RELAXED, __HIP_MEMORY_SCOPE_AGENT);
}
__device__ __forceinline__ void asto(ull* p, ull v) {
  __hip_atomic_store(p, v, __ATOMIC_RELAXED, __HIP_MEMORY_SCOPE_AGENT);
}
__device__ __forceinline__ float cload(const float* p) {
  return __hip_atomic_load(p, __ATOMIC_RELAXED, __HIP_MEMORY_SCOPE_AGENT);
}
__device__ __forceinline__ void cstore(float* p, float v) {
  __hip_atomic_store(p, v, __ATOMIC_RELAXED, __HIP_MEMORY_SCOPE_AGENT);
}

__global__ __launch_bounds__(TPB)
void glacier_kernel(const float* __restrict__ Zt,
                    const float* __restrict__ precip,
                    const float* __restrict__ Tm,
                    const float* __restrict__ Ts,
                    float* __restrict__ out,        // [3*MM]: H1, H2, H
                    ull* __restrict__ ring,         // [2][64] lines
                    float* __restrict__ Ha, float* __restrict__ Hb,
                    float* __restrict__ Da, float* __restrict__ Db) {
  // seam tables [wave 0..15][slot]; e* by lane0, w* by lane63 (within band)
  __shared__ float eZS[16][8], wZS[16][8], wD[16][8], eHN[16][8], eZN[16][8];
  __shared__ float wmax[16];
  __shared__ float gmaxS;
  // intra-block band seam (previous-step values, read at step top):
  __shared__ float iHab[NN], iDab[NN];  // bandA -> bandB (H row aB+2, D row aB+2)
  __shared__ float iHba[NN], iDba[NN];  // bandB -> bandA (H row aB+5, D row aB+4)

  const int tid = threadIdx.x;
  const int w = blockIdx.x;
  const int bb = tid >> 9;            // band 0/1
  const int j = tid & 511;            // column
  const int lane = tid & 63;
  const int wv = tid >> 6;            // 0..15
  const int wv0 = bb * 8;
  const int wvm = (wv == wv0) ? wv : wv - 1;
  const int wvp = (wv == wv0 + 7) ? wv : wv + 1;
  const int aB = w * 8;
  const int al = aB + 4 * bb;         // band first owned row
  const float TmTs = Tm[0] + Ts[0];
  const double RG = 910.0 * 9.81;
  const float CDIF = (float)(1e-16 * RG * RG * RG);

  float zt[8], zs[8];                 // rows al-2 .. al+5
  float h[6], smbr[6];                // rows al-1 .. al+4
  float Dv[7];                        // D rows al-2 .. al+4

  // ---- prologue (no cross-block deps)
#pragma unroll
  for (int s = 0; s < 8; ++s) {
    int r = al - 2 + s;
    zt[s] = (r >= 0 && r < NN) ? Zt[r * NN + j] : 0.f;
    zs[s] = zt[s];                    // H = 0
  }
#pragma unroll
  for (int ln = 0; ln < 6; ++ln) {
    int r = al - 1 + ln;
    h[ln] = 0.f;
    float sm = 0.f;
    if (r >= 0 && r < NN) {
      float T = TmTs - 0.006f * zt[ln + 1];
      sm = precip[r * NN + j] - 0.5f * fmaxf(T, 0.f);
    }
    smbr[ln] = sm;
  }
#pragma unroll
  for (int ld = 0; ld < 7; ++ld) Dv[ld] = 1e-10f;           // D(H=0) exactly
#pragma unroll
  for (int rr = 0; rr < 4; ++rr) {
    int id = (al + rr) * NN + j;
    out[id] = 0.f;
    out[MM + id] = 0.f;
  }
  if (tid < NN) { iHab[tid] = 0.f; iHba[tid] = 0.f;
                  iDab[tid] = 1e-10f; iDba[tid] = 1e-10f; }
  if (lane == 0) {
#pragma unroll
    for (int s = 1; s <= 6; ++s) eZS[wv][s] = zs[s];
  }
  if (lane == 63) {
#pragma unroll
    for (int s = 1; s <= 6; ++s) wZS[wv][s] = zs[s];
#pragma unroll
    for (int ld = 1; ld <= 5; ++ld) wD[wv][ld] = Dv[ld];
  }
  __syncthreads();

  float time = 0.f, t_last = 0.f;
  int idx = 0;
  bool s1 = false, s2 = false;

  for (int k = 0; k < NSTEPS; ++k) {
    if (time >= 200.0f) break;                  // uniform (dt identical)

    const float* Hrd = (k & 1) ? Hb : Ha;
    float* Hwr = (k & 1) ? Ha : Hb;
    const float* Drd = (k & 1) ? Db : Da;
    float* Dwr = (k & 1) ? Da : Db;
    ull* ringp = ring + (size_t)(k & 1) * NBLK * 16;

    // ---- top samples (issue early)
    bool pre = (time - t_last) >= 4.0f;         // exact-safe precip gate
    int idxn = min(idx + 1, 63);
    float pf[6];
    if (pre) {
      const float* prowN = precip + (size_t)idxn * MM;
#pragma unroll
      for (int ln = 0; ln < 6; ++ln) {
        int i = al - 1 + ln;
        pf[ln] = (i >= 0 && i < NN) ? prowN[i * NN + j] : 0.f;
      }
    } else {
#pragma unroll
      for (int ln = 0; ln < 6; ++ln) pf[ln] = 0.f;
    }
    // external-neighbor flag sample (bandA: w-1, bandB: w+1), gather sample
    const bool extOK = (bb == 0) ? (w > 0) : (w < NBLK - 1);
    const ull* np = nullptr; ull ns = 0;
    const ull* gp = nullptr; ull gv = 0;
    if (k > 0) {
      if (lane == 0 && extOK) {
        int nb = (bb == 0) ? w - 1 : w + 1;
        np = ringp + nb * 16; ns = ald(np);
      }
      if (tid < NBLK) { gp = ringp + tid * 16; gv = ald(gp); }
    }
    asm volatile("" ::: "memory");

    // ---- intra-block seam staging (previous-step values; ordered by sync3/prologue)
    if (bb == 0) { zs[7] = zt[7] + iHba[j]; Dv[6] = iDba[j]; }   // rows aB+5, aB+4
    else         { zs[0] = zt[0] + iHab[j]; Dv[0] = iDab[j]; }   // rows aB+2, aB+2

    // ---- W/E neighbor values via shfl + seams (halo-independent rows)
    float zsW[8], zsE[8], dWl[7];
#pragma unroll
    for (int s = 1; s <= 6; ++s) {
      float up = __shfl_up(zs[s], 1);
      float dn = __shfl_down(zs[s], 1);
      zsW[s] = (lane == 0) ? wZS[wvm][s] : up;
      zsE[s] = (lane == 63) ? eZS[wvp][s] : dn;
    }
#pragma unroll
    for (int ld = 1; ld <= 5; ++ld) {
      float up = __shfl_up(Dv[ld], 1);
      dWl[ld] = (lane == 0) ? wD[wvm][ld] : up;
    }

    // ---- mid dHdt rows al..al+3 (halo-free; hides flag-sample RT)
    float dH[6];
#pragma unroll
    for (int ln = 1; ln <= 4; ++ln) {
      int i = al - 1 + ln;
      float v = 0.f;
      if (i > 0 && i < NN - 1 && j > 0 && j < NN - 1) {
        float zc = zs[ln + 1], zw = zsW[ln + 1], ze = zsE[ln + 1];
        float zn = zs[ln], zso = zs[ln + 2];
        float d00 = dWl[ln], d01 = Dv[ln], d10 = dWl[ln + 1], d11 = Dv[ln + 1];
        float qx0 = -(0.5f * (d00 + d10)) * (zc - zw) / 200.f;
        float qx1 = -(0.5f * (d01 + d11)) * (ze - zc) / 200.f;
        float qy0 = -(0.5f * (d00 + d01)) * (zc - zn) / 200.f;
        float qy1 = -(0.5f * (d10 + d11)) * (zso - zc) / 200.f;
        v = -((qx1 - qx0) / 200.f + (qy1 - qy0) / 200.f);
      }
      dH[ln] = v;
    }

    // ---- flag spin -> external halo cloads -> gather spin (RTs overlap)
    if (k > 0) {
      if (np) {
        while ((unsigned)(ns >> 32) < (unsigned)k) {
          __builtin_amdgcn_s_sleep(1);
          ns = ald(np);
        }
      }
      asm volatile("" ::: "memory");            // cloads stay after the spin
      float hx = 0.f, dx = 0.f;
      if (extOK) {
        if (bb == 0) {                          // top external: rows aB-2
          hx = cload(Hrd + (al - 2) * NN + j);
          dx = cload(Drd + (al - 2) * NN + j);
        } else {                                // bottom external: rows aB+9, aB+8
          hx = cload(Hrd + (al + 5) * NN + j);
          dx = cload(Drd + (al + 4) * NN + j);
        }
      }
      if (tid < NBLK) {                         // direct gather (wave 0)
        while ((unsigned)(gv >> 32) < (unsigned)k) {
          __builtin_amdgcn_s_sleep(1);
          gv = ald(gp);
        }
        float lm = __uint_as_float((unsigned)gv);
        for (int off = 32; off; off >>= 1) lm = fmaxf(lm, __shfl_xor(lm, off));
        if (tid == 0) gmaxS = lm;
      }
      if (extOK) {
        if (bb == 0) { zs[0] = zt[0] + hx; Dv[0] = dx; }
        else         { zs[7] = zt[7] + hx; Dv[6] = dx; }
      }
    }
    if (lane == 63) { wD[wv][0] = Dv[0]; wD[wv][6] = Dv[6]; }
    __syncthreads();                            // sync1: halo D seams + gmaxS

    // ---- edge dHdt rows al-1 (ln=0: D ld 0,1) and al+4 (ln=5: D ld 5,6)
    {
      float up0 = __shfl_up(Dv[0], 1);
      float up6 = __shfl_up(Dv[6], 1);
      float dW0 = (lane == 0) ? wD[wvm][0] : up0;
      float dW6 = (lane == 0) ? wD[wvm][6] : up6;
#pragma unroll
      for (int e = 0; e < 2; ++e) {
        int ln = (e == 0) ? 0 : 5;
        int i = al - 1 + ln;
        float v = 0.f;
        if (i > 0 && i < NN - 1 && j > 0 && j < NN - 1) {
          float zc = zs[ln + 1], zw = zsW[ln + 1], ze = zsE[ln + 1];
          float zn = zs[ln], zso = zs[ln + 2];
          float d00 = (e == 0) ? dW0    : dWl[5];        // D row i-1, west
          float d01 = (e == 0) ? Dv[0]  : Dv[5];         // D row i-1
          float d10 = (e == 0) ? dWl[1] : dW6;           // D row i,   west
          float d11 = (e == 0) ? Dv[1]  : Dv[6];         // D row i
          float qx0 = -(0.5f * (d00 + d10)) * (zc - zw) / 200.f;
          float qx1 = -(0.5f * (d01 + d11)) * (ze - zc) / 200.f;
          float qy0 = -(0.5f * (d00 + d01)) * (zc - zn) / 200.f;
          float qy1 = -(0.5f * (d10 + d11)) * (zso - zc) / 200.f;
          v = -((qx1 - qx0) / 200.f + (qy1 - qy0) / 200.f);
        }
        dH[ln] = v;
      }
    }

    float maxD = (k == 0) ? 1e-10f : gmaxS;
    float dt = fminf(40000.0f / (2.7f * maxD), 1.0f);
    float tnew = time + dt;
    bool cap1 = (!s1) && (tnew >= 120.0f);
    bool cap2 = (!s2) && (tnew >= 160.0f);
    bool do_upd = (tnew - t_last) >= 5.0f;

    // ---- part B: H update, publishes, captures, smb refresh (registers)
    float hn[6], zsn[6];
#pragma unroll
    for (int ln = 0; ln < 6; ++ln) {
      int i = al - 1 + ln;
      float hnew = 0.f;
      if (i >= 0 && i < NN) {
        if (i > 0 && i < NN - 1 && j > 0 && j < NN - 1)
          hnew = fmaxf(h[ln] + dt * (dH[ln] + smbr[ln]), 0.f);
        float z = zt[ln + 1] + hnew;
        zsn[ln] = z;
        if (i == al + 1 + bb) cstore(Hwr + i * NN + j, hnew);  // external publish
        if (i >= al && i < al + 4) {
          int id = i * NN + j;
          if (cap1) out[id] = hnew;
          if (cap2) out[MM + id] = hnew;
        }
        if (do_upd)
          smbr[ln] = pf[ln] - 0.5f * fmaxf(TmTs - 0.006f * z, 0.f);
      } else {
        zsn[ln] = zt[ln + 1];                   // hnew = 0
      }
      hn[ln] = hnew;
    }
    // intra-block seam H: bandA row aB+2 (ln=3) -> iHab; bandB row aB+5 (ln=2) -> iHba
    if (bb == 0) iHab[j] = hn[3]; else iHba[j] = hn[2];
    if (lane == 0) {
#pragma unroll
      for (int ln = 0; ln < 6; ++ln) { eHN[wv][ln] = hn[ln]; eZN[wv][ln] = zsn[ln]; }
    }
    __syncthreads();                            // sync2: hn/zsn east seams

    // ---- phase 2: new D rows al-1..al+3 (registers+shfl) + block max
    float hnE[6], znE[6];
#pragma unroll
    for (int ln = 0; ln < 6; ++ln) {
      float hdn = __shfl_down(hn[ln], 1);
      float zdn = __shfl_down(zsn[ln], 1);
      hnE[ln] = (lane == 63) ? eHN[wvp][ln] : hdn;
      znE[ln] = (lane == 63) ? eZN[wvp][ln] : zdn;
    }
    float lmax = 0.f;
#pragma unroll
    for (int ln = 0; ln < 5; ++ln) {
      int r = al - 1 + ln;
      if (r >= 0 && r < NN - 1 && j < NN - 1) {
        float h00 = hn[ln], h01 = hnE[ln], h10 = hn[ln + 1], h11 = hnE[ln + 1];
        float z00 = zsn[ln], z01 = znE[ln], z10 = zsn[ln + 1], z11 = znE[ln + 1];
        float havg = 0.25f * (((h00 + h11) + h01) + h10);
        float sx = 0.5f * ((z01 - z00) / 200.f + (z11 - z10) / 200.f);
        float sy = 0.5f * ((z10 - z00) / 200.f + (z11 - z01) / 200.f);
        float sn = sqrtf((sx * sx + sy * sy) + 1e-10f);
        float h2 = havg * havg;
        float h4 = h2 * h2;
        float h5 = h4 * havg;
        float d = CDIF * h5 * (sn * sn) + 1e-10f;
        Dv[ln + 1] = d;
        if (r == al + 2 * bb) cstore(Dwr + r * NN + j, d);     // external publish
        // intra-block seam D: bandA row aB+2 (ln=3) -> iDab; bandB row aB+4 (ln=1) -> iDba
        if (bb == 0) { if (ln == 3) iDab[j] = d; }
        else         { if (ln == 1) iDba[j] = d; }
        lmax = fmaxf(lmax, d);
      }
    }
    for (int off = 32; off; off >>= 1) lmax = fmaxf(lmax, __shfl_xor(lmax, off));
    if (lane == 0) wmax[wv] = lmax;

    // ---- state roll + next-step seams (merged into sync3)
#pragma unroll
    for (int ln = 0; ln < 6; ++ln) h[ln] = hn[ln];
#pragma unroll
    for (int s = 1; s <= 6; ++s) zs[s] = zsn[s - 1];
    if (lane == 0) {
#pragma unroll
      for (int s = 1; s <= 6; ++s) eZS[wv][s] = zs[s];
    }
    if (lane == 63) {
#pragma unroll
      for (int s = 1; s <= 6; ++s) wZS[wv][s] = zs[s];
#pragma unroll
      for (int ld = 1; ld <= 5; ++ld) wD[wv][ld] = Dv[ld];
    }
    __syncthreads();    // sync3: wmax + seams; drains publishes (vmcnt)
    if (tid == 0) {
      float bm = wmax[0];
#pragma unroll
      for (int q = 1; q < 16; ++q) bm = fmaxf(bm, wmax[q]);
      asto(ring + (size_t)((k + 1) & 1) * NBLK * 16 + w * 16,
           ((ull)(unsigned)(k + 1) << 32) | __float_as_uint(bm));
    }

    // ---- bookkeeping
    time = tnew;
    s1 = s1 || cap1;
    s2 = s2 || cap2;
    if (do_upd) { idx = idxn; t_last = tnew; }
  }

  // ---- final H (owned rows al+rr -> h slot rr+1)
#pragma unroll
  for (int rr = 0; rr < 4; ++rr)
    out[2 * MM + (al + rr) * NN + j] = h[rr + 1];
}

extern "C" void kernel_launch(void* const* d_in, const int* in_sizes, int n_in,
                              void* d_out, int out_size, void* d_ws, size_t ws_size,
                              hipStream_t stream) {
  const float* Zt = (const float*)d_in[0];
  const float* precip = (const float*)d_in[1];
  const float* Tm = (const float*)d_in[2];
  const float* Ts = (const float*)d_in[3];
  float* out = (float*)d_out;

  ull* ring = (ull*)d_ws;                            // 2*64 lines @ 128 B
  float* Ha = (float*)((char*)d_ws + 32768);
  float* Hb = Ha + MM;
  float* Da = Hb + MM;
  float* Db = Da + MM;

  hipMemsetAsync(d_ws, 0, 16384, stream);            // ring tags -> 0
  glacier_kernel<<<NBLK, TPB, 0, stream>>>(Zt, precip, Tm, Ts, out,
                                           ring, Ha, Hb, Da, Db);
}

// Round 9
// 2177.524 us; speedup vs baseline: 2.0302x; 2.0302x over previous
//
#include <hip/hip_runtime.h>
#include <math.h>

// Glacier SIA stepper. 128 persistent blocks x 512 threads (R5 structure) with
// EPOCH-TAGGED halo exchange: each halo element is a ull {epoch<<32|float}
// stored by one relaxed 8B agent-scope atomic. No flags, no flag->data RT
// chain, no ordering needed -> halos post EARLY (inside part B / phase 2).
// Parity-2 halo buffers are race-free because the per-step maxD ring gather
// bounds global skew to <1 step at sync3 boundaries. maxD ring slot is posted
// pre-barrier by the last-finishing wave (LDS atomicMax + arrival counter).
//
// ws layout (bytes):
//   0      : ull ring[2][128] lines (stride 128 B) {epoch<<32 | blockMax}
//   32768  : ull halo[4][2][NW][NN]  (upH, upD, dnH, dnD; 4 MB)
// First 32768+4MB zeroed by captured hipMemsetAsync each call (tags -> 0).

#define NN 512
#define MM (NN * NN)
#define NSTEPS 400
#define NW 128
#define HR 4
#define TPB 512

typedef unsigned long long ull;

__device__ __forceinline__ ull ald(const ull* p) {
  return __hip_atomic_load(p, __ATOMIC_RELAXED, __HIP_MEMORY_SCOPE_AGENT);
}
__device__ __forceinline__ void asto(ull* p, ull v) {
  __hip_atomic_store(p, v, __ATOMIC_RELAXED, __HIP_MEMORY_SCOPE_AGENT);
}

__global__ __launch_bounds__(TPB)
void glacier_kernel(const float* __restrict__ Zt,
                    const float* __restrict__ precip,
                    const float* __restrict__ Tm,
                    const float* __restrict__ Ts,
                    float* __restrict__ out,        // [3*MM]: H1, H2, H
                    ull* __restrict__ ring,         // [2][128] lines
                    ull* __restrict__ halo) {       // [4][2][NW][NN]
  __shared__ float Zs2[2][HR + 4][NN];
  __shared__ float DB[HR + 3][NN];
  __shared__ float HnB[HR + 2][NN];
  __shared__ float gmax2[2];
  __shared__ unsigned lmx[2], lcnt[2];

  ull* upH = halo;                    // [2][NW][NN] each
  ull* upD = halo + 2 * NW * NN;
  ull* dnH = halo + 4 * NW * NN;
  ull* dnD = halo + 6 * NW * NN;

  const int w = blockIdx.x;
  const int j = threadIdx.x;          // column
  const int lane = j & 63;
  const int a = w * HR;               // first owned row
  const bool hasT = (w > 0), hasB = (w < NW - 1);
  const float TmTs = Tm[0] + Ts[0];
  const double RG = 910.0 * 9.81;
  const float CDIF = (float)(1e-16 * RG * RG * RG);
  const size_t wofs = (size_t)w * NN;

  float ztreg[HR + 4];
  float hcur[HR + 2];
  float smbreg[HR + 2];

  // ---- prologue (no cross-block deps)
#pragma unroll
  for (int ls = 0; ls < HR + 4; ++ls) {
    int r = a - 2 + ls;
    float zt = (r >= 0 && r < NN) ? Zt[r * NN + j] : 0.f;
    ztreg[ls] = zt;
    Zs2[0][ls][j] = zt;               // H = 0
  }
#pragma unroll
  for (int ln = 0; ln < HR + 2; ++ln) {
    int r = a - 1 + ln;
    hcur[ln] = 0.f;
    float sm = 0.f;
    if (r >= 0 && r < NN) {
      float T = TmTs - 0.006f * ztreg[ln + 1];
      sm = precip[r * NN + j] - 0.5f * fmaxf(T, 0.f);
    }
    smbreg[ln] = sm;
  }
#pragma unroll
  for (int ld = 0; ld < HR + 3; ++ld) DB[ld][j] = 1e-10f;    // D(H=0) exactly
#pragma unroll
  for (int rr = 0; rr < HR; ++rr) {
    int id = (a + rr) * NN + j;
    out[id] = 0.f;
    out[MM + id] = 0.f;
  }
  if (j == 0) { lmx[0] = 0u; lmx[1] = 0u; lcnt[0] = 0u; lcnt[1] = 0u; }
  __syncthreads();                    // prologue LDS visible

  float time = 0.f, t_last = 0.f;
  int idx = 0;
  bool s1 = false, s2 = false;

  for (int k = 0; k < NSTEPS; ++k) {
    if (time >= 200.0f) break;                  // uniform (dt identical)

    const int p = k & 1;
    const size_t pc = (size_t)(k & 1) * NW * NN;        // consume parity
    const size_t pn = (size_t)((k + 1) & 1) * NW * NN;  // produce parity
    const ull tg = ((ull)(unsigned)(k + 1)) << 32;      // produce tag
    ull* ringp = ring + (size_t)(k & 1) * NW * 16;

    // reset the LDS max/cnt slot step k+1 will use (safe: sync3(k-1) passed)
    if (j == 0) { lmx[(k + 1) & 1] = 0u; lcnt[(k + 1) & 1] = 0u; }

    // ---- top samples (issue early; checked after mid compute)
    bool pre = (time - t_last) >= 4.0f;         // exact-safe precip gate
    int idxn = min(idx + 1, 63);
    float pf[HR + 2];
    if (pre) {
      const float* prowN = precip + (size_t)idxn * MM;
#pragma unroll
      for (int ln = 0; ln < HR + 2; ++ln) {
        int i = a - 1 + ln;
        pf[ln] = (i >= 0 && i < NN) ? prowN[i * NN + j] : 0.f;
      }
    } else {
#pragma unroll
      for (int ln = 0; ln < HR + 2; ++ln) pf[ln] = 0.f;
    }
    const ull *pHt = nullptr, *pDt = nullptr, *pHb = nullptr, *pDb = nullptr;
    ull vHt = 0, vDt = 0, vHb = 0, vDb = 0;
    const ull* gp = nullptr; ull gv = 0;
    if (k > 0) {
      if (hasT) {
        pHt = dnH + pc + (size_t)(w - 1) * NN + j;
        pDt = dnD + pc + (size_t)(w - 1) * NN + j;
        vHt = ald(pHt);
        if (j < NN - 1) vDt = ald(pDt);
      }
      if (hasB) {
        pHb = upH + pc + (size_t)(w + 1) * NN + j;
        pDb = upD + pc + (size_t)(w + 1) * NN + j;
        vHb = ald(pHb);
        if (j < NN - 1) vDb = ald(pDb);
      }
      if (j < NW) { gp = ringp + j * 16; gv = ald(gp); }   // gather sample
    }
    asm volatile("" ::: "memory");

    // ---- part A mid: dHdt rows a..a+3 (halo-free; hides sample RTs)
    float dHdt[HR + 2];
#pragma unroll
    for (int ln = 1; ln <= HR; ++ln) {
      int i = a - 1 + ln;
      float v = 0.f;
      if (i > 0 && i < NN - 1 && j > 0 && j < NN - 1) {
        int li = ln + 1;
        float zc = Zs2[p][li][j];
        float zw = Zs2[p][li][j - 1];
        float ze = Zs2[p][li][j + 1];
        float zn = Zs2[p][li - 1][j];
        float zs_ = Zs2[p][li + 1][j];
        float d00 = DB[ln][j - 1], d01 = DB[ln][j];
        float d10 = DB[ln + 1][j - 1], d11 = DB[ln + 1][j];
        float qx0 = -(0.5f * (d00 + d10)) * (zc - zw) / 200.f;
        float qx1 = -(0.5f * (d01 + d11)) * (ze - zc) / 200.f;
        float qy0 = -(0.5f * (d00 + d01)) * (zc - zn) / 200.f;
        float qy1 = -(0.5f * (d10 + d11)) * (zs_ - zc) / 200.f;
        v = -((qx1 - qx0) / 200.f + (qy1 - qy0) / 200.f);
      }
      dHdt[ln] = v;
    }

    // ---- halo tag checks (data+readiness in one word) + gather spin
    if (k > 0) {
      if (pHt) {
        while ((unsigned)(vHt >> 32) < (unsigned)k) {
          __builtin_amdgcn_s_sleep(1); vHt = ald(pHt);
        }
        if (j < NN - 1)
          while ((unsigned)(vDt >> 32) < (unsigned)k) {
            __builtin_amdgcn_s_sleep(1); vDt = ald(pDt);
          }
      }
      if (pHb) {
        while ((unsigned)(vHb >> 32) < (unsigned)k) {
          __builtin_amdgcn_s_sleep(1); vHb = ald(pHb);
        }
        if (j < NN - 1)
          while ((unsigned)(vDb >> 32) < (unsigned)k) {
            __builtin_amdgcn_s_sleep(1); vDb = ald(pDb);
          }
      }
      if (j < NW) {                             // direct gather (waves 0,1)
        while ((unsigned)(gv >> 32) < (unsigned)k) {
          __builtin_amdgcn_s_sleep(1); gv = ald(gp);
        }
        float lm = __uint_as_float((unsigned)gv);
        for (int off = 32; off; off >>= 1) lm = fmaxf(lm, __shfl_xor(lm, off));
        if (lane == 0) gmax2[j >> 6] = lm;
      }
      // stage halos into LDS
      if (pHt) {
        Zs2[p][0][j] = ztreg[0] + __uint_as_float((unsigned)vHt);
        if (j < NN - 1) DB[0][j] = __uint_as_float((unsigned)vDt);
      }
      if (pHb) {
        Zs2[p][HR + 3][j] = ztreg[HR + 3] + __uint_as_float((unsigned)vHb);
        if (j < NN - 1) DB[HR + 2][j] = __uint_as_float((unsigned)vDb);
      }
    }
    __syncthreads();                            // sync1: halos + gmax2 visible

    // ---- part A edges: dHdt rows a-1, a+4
#pragma unroll
    for (int ln = 0; ln <= HR + 1; ln += HR + 1) {
      int i = a - 1 + ln;
      float v = 0.f;
      if (i > 0 && i < NN - 1 && j > 0 && j < NN - 1) {
        int li = ln + 1;
        float zc = Zs2[p][li][j];
        float zw = Zs2[p][li][j - 1];
        float ze = Zs2[p][li][j + 1];
        float zn = Zs2[p][li - 1][j];
        float zs_ = Zs2[p][li + 1][j];
        float d00 = DB[ln][j - 1], d01 = DB[ln][j];
        float d10 = DB[ln + 1][j - 1], d11 = DB[ln + 1][j];
        float qx0 = -(0.5f * (d00 + d10)) * (zc - zw) / 200.f;
        float qx1 = -(0.5f * (d01 + d11)) * (ze - zc) / 200.f;
        float qy0 = -(0.5f * (d00 + d01)) * (zc - zn) / 200.f;
        float qy1 = -(0.5f * (d10 + d11)) * (zs_ - zc) / 200.f;
        v = -((qx1 - qx0) / 200.f + (qy1 - qy0) / 200.f);
      }
      dHdt[ln] = v;
    }

    float maxD = (k == 0) ? 1e-10f : fmaxf(gmax2[0], gmax2[1]);
    float dt = fminf(40000.0f / (2.7f * maxD), 1.0f);
    float tnew = time + dt;
    bool cap1 = (!s1) && (tnew >= 120.0f);
    bool cap2 = (!s2) && (tnew >= 160.0f);
    bool do_upd = (tnew - t_last) >= 5.0f;

    // ---- part B: H update, EARLY tagged H-halo posts, captures, smb
    float hnxt[HR + 2];
#pragma unroll
    for (int ln = 0; ln < HR + 2; ++ln) {
      int i = a - 1 + ln;
      float hnew = 0.f;
      if (i >= 0 && i < NN) {
        if (i > 0 && i < NN - 1 && j > 0 && j < NN - 1)
          hnew = fmaxf(hcur[ln] + dt * (dHdt[ln] + smbreg[ln]), 0.f);
        float zsn = ztreg[ln + 1] + hnew;
        HnB[ln][j] = hnew;
        Zs2[p ^ 1][ln + 1][j] = zsn;
        if (ln == 2) asto(upH + pn + wofs + j, tg | (ull)__float_as_uint(hnew));
        if (ln == 3) asto(dnH + pn + wofs + j, tg | (ull)__float_as_uint(hnew));
        if (i >= a && i < a + HR) {
          int id = i * NN + j;
          if (cap1) out[id] = hnew;
          if (cap2) out[MM + id] = hnew;
        }
        if (do_upd)
          smbreg[ln] = pf[ln] - 0.5f * fmaxf(TmTs - 0.006f * zsn, 0.f);
      }
      hnxt[ln] = hnew;
    }
    __syncthreads();                            // sync2: HnB/Zs2^1 visible

    // ---- phase 2: new D rows a-1..a+3 + EARLY tagged D-halo posts + max
    float lmax = 0.f;
#pragma unroll
    for (int ln = 0; ln < HR + 1; ++ln) {
      int r = a - 1 + ln;
      if (r >= 0 && r < NN - 1 && j < NN - 1) {
        float h00 = HnB[ln][j], h01 = HnB[ln][j + 1];
        float h10 = HnB[ln + 1][j], h11 = HnB[ln + 1][j + 1];
        float z00 = Zs2[p ^ 1][ln + 1][j], z01 = Zs2[p ^ 1][ln + 1][j + 1];
        float z10 = Zs2[p ^ 1][ln + 2][j], z11 = Zs2[p ^ 1][ln + 2][j + 1];
        float havg = 0.25f * (((h00 + h11) + h01) + h10);
        float sx = 0.5f * ((z01 - z00) / 200.f + (z11 - z10) / 200.f);
        float sy = 0.5f * ((z10 - z00) / 200.f + (z11 - z01) / 200.f);
        float sn = sqrtf((sx * sx + sy * sy) + 1e-10f);
        float h2 = havg * havg;
        float h4 = h2 * h2;
        float h5 = h4 * havg;
        float d = CDIF * h5 * (sn * sn) + 1e-10f;
        DB[ln + 1][j] = d;
        if (ln == 1) asto(upD + pn + wofs + j, tg | (ull)__float_as_uint(d));
        if (ln == 3) asto(dnD + pn + wofs + j, tg | (ull)__float_as_uint(d));
        lmax = fmaxf(lmax, d);
      }
    }
    for (int off = 32; off; off >>= 1) lmax = fmaxf(lmax, __shfl_xor(lmax, off));
    // pre-barrier ring post: last-arriving wave publishes the block max
    if (lane == 0) {
      atomicMax(&lmx[k & 1], __float_as_uint(lmax));   // D>0: uint-monotone
      unsigned c = atomicAdd(&lcnt[k & 1], 1u);
      if (c == 7u) {
        unsigned mv = atomicAdd(&lmx[k & 1], 0u);      // atomic read-back
        asto(ring + (size_t)((k + 1) & 1) * NW * 16 + w * 16,
             ((ull)(unsigned)(k + 1) << 32) | (ull)mv);
      }
    }

    // ---- bookkeeping + step-close barrier (protects LDS reuse next step)
#pragma unroll
    for (int ln = 0; ln < HR + 2; ++ln) hcur[ln] = hnxt[ln];
    time = tnew;
    s1 = s1 || cap1;
    s2 = s2 || cap2;
    if (do_upd) { idx = idxn; t_last = tnew; }
    __syncthreads();                            // sync3
  }

  // ---- final H (owned rows; hcur slot for row a+rr is rr+1)
#pragma unroll
  for (int rr = 0; rr < HR; ++rr)
    out[2 * MM + (a + rr) * NN + j] = hcur[rr + 1];
}

extern "C" void kernel_launch(void* const* d_in, const int* in_sizes, int n_in,
                              void* d_out, int out_size, void* d_ws, size_t ws_size,
                              hipStream_t stream) {
  const float* Zt = (const float*)d_in[0];
  const float* precip = (const float*)d_in[1];
  const float* Tm = (const float*)d_in[2];
  const float* Ts = (const float*)d_in[3];
  float* out = (float*)d_out;

  ull* ring = (ull*)d_ws;                            // 2*128 lines @ 128 B
  ull* halo = (ull*)((char*)d_ws + 32768);           // 4 MB tagged halos

  // zero ring tags + halo tags (ws is not re-poisoned between replays)
  hipMemsetAsync(d_ws, 0, 32768 + (size_t)8 * NW * NN * sizeof(ull), stream);
  glacier_kernel<<<NW, TPB, 0, stream>>>(Zt, precip, Tm, Ts, out, ring, halo);
}

// Round 10
// 1275.561 us; speedup vs baseline: 3.4657x; 1.7071x over previous
//
#include <hip/hip_runtime.h>
#include <math.h>

// Glacier SIA stepper. 128 persistent blocks x 512 threads (R9 protocol,
// strength-reduced arithmetic). Epoch-tagged halo words {epoch<<32|float}
// posted EARLY (inside part B / phase 2) via relaxed 8B agent-scope atomics;
// depth-2 parity buffers; direct 128-wide ring gather; pre-barrier ring post.
// Arithmetic: /200 scalings folded into single constants (1.25e-5, 6.25e-6),
// sqrt^2 identity removed. dt formula kept as exact division.
//
// ws layout (bytes):
//   0      : ull ring[2][128] lines (stride 128 B) {epoch<<32 | blockMax}
//   32768  : ull halo[4][2][NW][NN]  (upH, upD, dnH, dnD; 4 MB)

#define NN 512
#define MM (NN * NN)
#define NSTEPS 400
#define NW 128
#define HR 4
#define TPB 512

typedef unsigned long long ull;

__device__ __forceinline__ ull ald(const ull* p) {
  return __hip_atomic_load(p, __ATOMIC_RELAXED, __HIP_MEMORY_SCOPE_AGENT);
}
__device__ __forceinline__ void asto(ull* p, ull v) {
  __hip_atomic_store(p, v, __ATOMIC_RELAXED, __HIP_MEMORY_SCOPE_AGENT);
}

__global__ __launch_bounds__(TPB)
void glacier_kernel(const float* __restrict__ Zt,
                    const float* __restrict__ precip,
                    const float* __restrict__ Tm,
                    const float* __restrict__ Ts,
                    float* __restrict__ out,        // [3*MM]: H1, H2, H
                    ull* __restrict__ ring,         // [2][128] lines
                    ull* __restrict__ halo) {       // [4][2][NW][NN]
  __shared__ float Zs2[2][HR + 4][NN];
  __shared__ float DB[HR + 3][NN];
  __shared__ float HnB[HR + 2][NN];
  __shared__ float gmax2[2];
  __shared__ unsigned lmx[2], lcnt[2];

  ull* upH = halo;                    // [2][NW][NN] each
  ull* upD = halo + 2 * NW * NN;
  ull* dnH = halo + 4 * NW * NN;
  ull* dnD = halo + 6 * NW * NN;

  const int w = blockIdx.x;
  const int j = threadIdx.x;          // column
  const int lane = j & 63;
  const int a = w * HR;               // first owned row
  const bool hasT = (w > 0), hasB = (w < NW - 1);
  const float TmTs = Tm[0] + Ts[0];
  const double RG = 910.0 * 9.81;
  const float CDIF = (float)(1e-16 * RG * RG * RG);
  const float C_Q = 1.25e-5f;         // 0.5 / (200*200*... folded flux scaling
  const float C_S2 = 6.25e-6f;        // (0.5/200)^2 slope scaling
  const size_t wofs = (size_t)w * NN;

  float ztreg[HR + 4];
  float hcur[HR + 2];
  float smbreg[HR + 2];

  // ---- prologue (no cross-block deps)
#pragma unroll
  for (int ls = 0; ls < HR + 4; ++ls) {
    int r = a - 2 + ls;
    float zt = (r >= 0 && r < NN) ? Zt[r * NN + j] : 0.f;
    ztreg[ls] = zt;
    Zs2[0][ls][j] = zt;               // H = 0
  }
#pragma unroll
  for (int ln = 0; ln < HR + 2; ++ln) {
    int r = a - 1 + ln;
    hcur[ln] = 0.f;
    float sm = 0.f;
    if (r >= 0 && r < NN) {
      float T = TmTs - 0.006f * ztreg[ln + 1];
      sm = precip[r * NN + j] - 0.5f * fmaxf(T, 0.f);
    }
    smbreg[ln] = sm;
  }
#pragma unroll
  for (int ld = 0; ld < HR + 3; ++ld) DB[ld][j] = 1e-10f;    // D(H=0) exactly
#pragma unroll
  for (int rr = 0; rr < HR; ++rr) {
    int id = (a + rr) * NN + j;
    out[id] = 0.f;
    out[MM + id] = 0.f;
  }
  if (j == 0) { lmx[0] = 0u; lmx[1] = 0u; lcnt[0] = 0u; lcnt[1] = 0u; }
  __syncthreads();                    // prologue LDS visible

  float time = 0.f, t_last = 0.f;
  int idx = 0;
  bool s1 = false, s2 = false;

  for (int k = 0; k < NSTEPS; ++k) {
    if (time >= 200.0f) break;                  // uniform (dt identical)

    const int p = k & 1;
    const size_t pc = (size_t)(k & 1) * NW * NN;        // consume parity
    const size_t pn = (size_t)((k + 1) & 1) * NW * NN;  // produce parity
    const ull tg = ((ull)(unsigned)(k + 1)) << 32;      // produce tag
    ull* ringp = ring + (size_t)(k & 1) * NW * 16;

    // reset the LDS max/cnt slot step k+1 will use (safe: sync3(k-1) passed)
    if (j == 0) { lmx[(k + 1) & 1] = 0u; lcnt[(k + 1) & 1] = 0u; }

    // ---- top samples (issue early; checked after mid compute)
    bool pre = (time - t_last) >= 4.0f;         // exact-safe precip gate
    int idxn = min(idx + 1, 63);
    float pf[HR + 2];
    if (pre) {
      const float* prowN = precip + (size_t)idxn * MM;
#pragma unroll
      for (int ln = 0; ln < HR + 2; ++ln) {
        int i = a - 1 + ln;
        pf[ln] = (i >= 0 && i < NN) ? prowN[i * NN + j] : 0.f;
      }
    } else {
#pragma unroll
      for (int ln = 0; ln < HR + 2; ++ln) pf[ln] = 0.f;
    }
    const ull *pHt = nullptr, *pDt = nullptr, *pHb = nullptr, *pDb = nullptr;
    ull vHt = 0, vDt = 0, vHb = 0, vDb = 0;
    const ull* gp = nullptr; ull gv = 0;
    if (k > 0) {
      if (hasT) {
        pHt = dnH + pc + (size_t)(w - 1) * NN + j;
        pDt = dnD + pc + (size_t)(w - 1) * NN + j;
        vHt = ald(pHt);
        if (j < NN - 1) vDt = ald(pDt);
      }
      if (hasB) {
        pHb = upH + pc + (size_t)(w + 1) * NN + j;
        pDb = upD + pc + (size_t)(w + 1) * NN + j;
        vHb = ald(pHb);
        if (j < NN - 1) vDb = ald(pDb);
      }
      if (j < NW) { gp = ringp + j * 16; gv = ald(gp); }   // gather sample
    }
    asm volatile("" ::: "memory");

    // ---- part A mid: dHdt rows a..a+3 (halo-free; hides sample RTs)
    float dHdt[HR + 2];
#pragma unroll
    for (int ln = 1; ln <= HR; ++ln) {
      int i = a - 1 + ln;
      float v = 0.f;
      if (i > 0 && i < NN - 1 && j > 0 && j < NN - 1) {
        int li = ln + 1;
        float zc = Zs2[p][li][j];
        float zw = Zs2[p][li][j - 1];
        float ze = Zs2[p][li][j + 1];
        float zn = Zs2[p][li - 1][j];
        float zs_ = Zs2[p][li + 1][j];
        float d00 = DB[ln][j - 1], d01 = DB[ln][j];
        float d10 = DB[ln + 1][j - 1], d11 = DB[ln + 1][j];
        v = C_Q * (((d01 + d11) * (ze - zc) - (d00 + d10) * (zc - zw)) +
                   ((d10 + d11) * (zs_ - zc) - (d00 + d01) * (zc - zn)));
      }
      dHdt[ln] = v;
    }

    // ---- halo tag checks (data+readiness in one word) + gather spin
    if (k > 0) {
      if (pHt) {
        while ((unsigned)(vHt >> 32) < (unsigned)k) {
          __builtin_amdgcn_s_sleep(1); vHt = ald(pHt);
        }
        if (j < NN - 1)
          while ((unsigned)(vDt >> 32) < (unsigned)k) {
            __builtin_amdgcn_s_sleep(1); vDt = ald(pDt);
          }
      }
      if (pHb) {
        while ((unsigned)(vHb >> 32) < (unsigned)k) {
          __builtin_amdgcn_s_sleep(1); vHb = ald(pHb);
        }
        if (j < NN - 1)
          while ((unsigned)(vDb >> 32) < (unsigned)k) {
            __builtin_amdgcn_s_sleep(1); vDb = ald(pDb);
          }
      }
      if (j < NW) {                             // direct gather (waves 0,1)
        while ((unsigned)(gv >> 32) < (unsigned)k) {
          __builtin_amdgcn_s_sleep(1); gv = ald(gp);
        }
        float lm = __uint_as_float((unsigned)gv);
        for (int off = 32; off; off >>= 1) lm = fmaxf(lm, __shfl_xor(lm, off));
        if (lane == 0) gmax2[j >> 6] = lm;
      }
      // stage halos into LDS
      if (pHt) {
        Zs2[p][0][j] = ztreg[0] + __uint_as_float((unsigned)vHt);
        if (j < NN - 1) DB[0][j] = __uint_as_float((unsigned)vDt);
      }
      if (pHb) {
        Zs2[p][HR + 3][j] = ztreg[HR + 3] + __uint_as_float((unsigned)vHb);
        if (j < NN - 1) DB[HR + 2][j] = __uint_as_float((unsigned)vDb);
      }
    }
    __syncthreads();                            // sync1: halos + gmax2 visible

    // ---- part A edges: dHdt rows a-1, a+4
#pragma unroll
    for (int ln = 0; ln <= HR + 1; ln += HR + 1) {
      int i = a - 1 + ln;
      float v = 0.f;
      if (i > 0 && i < NN - 1 && j > 0 && j < NN - 1) {
        int li = ln + 1;
        float zc = Zs2[p][li][j];
        float zw = Zs2[p][li][j - 1];
        float ze = Zs2[p][li][j + 1];
        float zn = Zs2[p][li - 1][j];
        float zs_ = Zs2[p][li + 1][j];
        float d00 = DB[ln][j - 1], d01 = DB[ln][j];
        float d10 = DB[ln + 1][j - 1], d11 = DB[ln + 1][j];
        v = C_Q * (((d01 + d11) * (ze - zc) - (d00 + d10) * (zc - zw)) +
                   ((d10 + d11) * (zs_ - zc) - (d00 + d01) * (zc - zn)));
      }
      dHdt[ln] = v;
    }

    float maxD = (k == 0) ? 1e-10f : fmaxf(gmax2[0], gmax2[1]);
    float dt = fminf(40000.0f / (2.7f * maxD), 1.0f);
    float tnew = time + dt;
    bool cap1 = (!s1) && (tnew >= 120.0f);
    bool cap2 = (!s2) && (tnew >= 160.0f);
    bool do_upd = (tnew - t_last) >= 5.0f;

    // ---- part B: H update, EARLY tagged H-halo posts, captures, smb
    float hnxt[HR + 2];
#pragma unroll
    for (int ln = 0; ln < HR + 2; ++ln) {
      int i = a - 1 + ln;
      float hnew = 0.f;
      if (i >= 0 && i < NN) {
        if (i > 0 && i < NN - 1 && j > 0 && j < NN - 1)
          hnew = fmaxf(hcur[ln] + dt * (dHdt[ln] + smbreg[ln]), 0.f);
        float zsn = ztreg[ln + 1] + hnew;
        HnB[ln][j] = hnew;
        Zs2[p ^ 1][ln + 1][j] = zsn;
        if (ln == 2) asto(upH + pn + wofs + j, tg | (ull)__float_as_uint(hnew));
        if (ln == 3) asto(dnH + pn + wofs + j, tg | (ull)__float_as_uint(hnew));
        if (i >= a && i < a + HR) {
          int id = i * NN + j;
          if (cap1) out[id] = hnew;
          if (cap2) out[MM + id] = hnew;
        }
        if (do_upd)
          smbreg[ln] = pf[ln] - 0.5f * fmaxf(TmTs - 0.006f * zsn, 0.f);
      }
      hnxt[ln] = hnew;
    }
    __syncthreads();                            // sync2: HnB/Zs2^1 visible

    // ---- phase 2: new D rows a-1..a+3 + EARLY tagged D-halo posts + max
    float lmax = 0.f;
#pragma unroll
    for (int ln = 0; ln < HR + 1; ++ln) {
      int r = a - 1 + ln;
      if (r >= 0 && r < NN - 1 && j < NN - 1) {
        float h00 = HnB[ln][j], h01 = HnB[ln][j + 1];
        float h10 = HnB[ln + 1][j], h11 = HnB[ln + 1][j + 1];
        float z00 = Zs2[p ^ 1][ln + 1][j], z01 = Zs2[p ^ 1][ln + 1][j + 1];
        float z10 = Zs2[p ^ 1][ln + 2][j], z11 = Zs2[p ^ 1][ln + 2][j + 1];
        float havg = 0.25f * (((h00 + h11) + h01) + h10);
        float u = (z01 - z00) + (z11 - z10);    // x-slope sum
        float vv = (z10 - z00) + (z11 - z01);   // y-slope sum
        float s2 = C_S2 * (u * u + vv * vv) + 1e-10f;  // == Snorm^2 (sqrt folded)
        float h2 = havg * havg;
        float h4 = h2 * h2;
        float h5 = h4 * havg;
        float d = CDIF * h5 * s2 + 1e-10f;
        DB[ln + 1][j] = d;
        if (ln == 1) asto(upD + pn + wofs + j, tg | (ull)__float_as_uint(d));
        if (ln == 3) asto(dnD + pn + wofs + j, tg | (ull)__float_as_uint(d));
        lmax = fmaxf(lmax, d);
      }
    }
    for (int off = 32; off; off >>= 1) lmax = fmaxf(lmax, __shfl_xor(lmax, off));
    // pre-barrier ring post: last-arriving wave publishes the block max
    if (lane == 0) {
      atomicMax(&lmx[k & 1], __float_as_uint(lmax));   // D>0: uint-monotone
      unsigned c = atomicAdd(&lcnt[k & 1], 1u);
      if (c == 7u) {
        unsigned mv = atomicAdd(&lmx[k & 1], 0u);      // atomic read-back
        asto(ring + (size_t)((k + 1) & 1) * NW * 16 + w * 16,
             ((ull)(unsigned)(k + 1) << 32) | (ull)mv);
      }
    }

    // ---- bookkeeping + step-close barrier (protects LDS reuse next step)
#pragma unroll
    for (int ln = 0; ln < HR + 2; ++ln) hcur[ln] = hnxt[ln];
    time = tnew;
    s1 = s1 || cap1;
    s2 = s2 || cap2;
    if (do_upd) { idx = idxn; t_last = tnew; }
    __syncthreads();                            // sync3
  }

  // ---- final H (owned rows; hcur slot for row a+rr is rr+1)
#pragma unroll
  for (int rr = 0; rr < HR; ++rr)
    out[2 * MM + (a + rr) * NN + j] = hcur[rr + 1];
}

extern "C" void kernel_launch(void* const* d_in, const int* in_sizes, int n_in,
                              void* d_out, int out_size, void* d_ws, size_t ws_size,
                              hipStream_t stream) {
  const float* Zt = (const float*)d_in[0];
  const float* precip = (const float*)d_in[1];
  const float* Tm = (const float*)d_in[2];
  const float* Ts = (const float*)d_in[3];
  float* out = (float*)d_out;

  ull* ring = (ull*)d_ws;                            // 2*128 lines @ 128 B
  ull* halo = (ull*)((char*)d_ws + 32768);           // 4 MB tagged halos

  // zero ring tags + halo tags (ws is not re-poisoned between replays)
  hipMemsetAsync(d_ws, 0, 32768 + (size_t)8 * NW * NN * sizeof(ull), stream);
  glacier_kernel<<<NW, TPB, 0, stream>>>(Zt, precip, Tm, Ts, out, ring, halo);
}